// Round 9
// baseline (170.569 us; speedup 1.0000x reference)
//
#include <hip/hip_runtime.h>
#include <hip/hip_cooperative_groups.h>

namespace cg = cooperative_groups;

constexpr int   ND_  = 16;
constexpr int   C_   = 512;
constexpr float EPS_ = 1e-5f;
constexpr int   RPC  = 512;   // rows per chunk

// ------------- Kernel 1: fused stats + finalize (cooperative) -------------
// 512 blocks x 256 thr, 67 KB LDS -> exactly 2 blocks/CU (coop-resident).
// Phase 1 = R8 k_stats (proven): block (bx=bid&3, by=bid>>2) covers channel
// quarter bx of row chunk by; 4 row-groups x 64 float2-lanes, per-group LDS
// accumulators, merged, dumped to partials. grid.sync. Phase 2 = R8
// k_finalize on blocks 0..255 (partials L2/L3-hot; overlaps stragglers).
// Saves the standalone finalize dispatch + one launch gap vs R8.
__global__ __launch_bounds__(256) void k_stats_fin(
    const float2* __restrict__ X2, const int* __restrict__ dd,
    const float* __restrict__ gamma, const float* __restrict__ beta,
    float* __restrict__ part_sum, float* __restrict__ part_sq,
    int* __restrict__ pcnt, float* __restrict__ scale,
    float* __restrict__ shift, int N) {
  __shared__ float2 ssum[4][ND_][64];   // 32 KB
  __shared__ float2 ssq [4][ND_][64];   // 32 KB
  __shared__ int    sd[RPC];            // 2 KB
  __shared__ int    scnt[ND_];
  __shared__ float  fsum[8][32];        // phase-2 tree (1 KB)
  __shared__ float  fsq [8][32];
  __shared__ int    fcnt[8];

  const int tid  = threadIdx.x;
  const int g    = tid >> 6;        // row-group 0..3
  const int lane = tid & 63;        // float2 lane within quarter
  const int bid  = blockIdx.x;
  const int bx   = bid & 3;         // channel quarter
  const int by   = bid >> 2;        // row chunk
  const int nchunk = (N + RPC - 1) / RPC;   // 128

  // ---------------- phase 1: per-chunk stats ----------------
  for (int i = tid; i < 4 * ND_ * 64; i += 256) {
    ((float2*)ssum)[i] = make_float2(0.f, 0.f);
    ((float2*)ssq )[i] = make_float2(0.f, 0.f);
  }
  if (tid < ND_) scnt[tid] = 0;
  __syncthreads();

  const int r0 = by * RPC;
  const int r1 = min(N, r0 + RPC);
  const int nr = r1 - r0;

  for (int i = tid; i < nr; i += 256) {
    const int v = dd[r0 + i];
    sd[i] = v;
    if (bx == 0) atomicAdd(&scnt[v], 1);
  }
  __syncthreads();

  const int jr0 = g * 128;
  const int jr1 = min(nr, jr0 + 128);
  const int ch2 = bx * 64 + lane;   // float2 column (row = 256 float2)
  #pragma unroll 8
  for (int j = jr0; j < jr1; ++j) {
    const int    dn = sd[j];        // wave-uniform
    const float2 v  = X2[(size_t)(r0 + j) * (C_ / 2) + ch2];
    float2 a = ssum[g][dn][lane];
    a.x += v.x; a.y += v.y;
    ssum[g][dn][lane] = a;
    float2 b = ssq[g][dn][lane];
    b.x = fmaf(v.x, v.x, b.x);
    b.y = fmaf(v.y, v.y, b.y);
    ssq[g][dn][lane] = b;
  }
  __syncthreads();

  // merge groups 1..3 into 0 (parallel over all 256 threads)
  for (int idx = tid; idx < ND_ * 64; idx += 256) {
    const int dom = idx >> 6;
    const int ln  = idx & 63;
    float2 a = ssum[0][dom][ln];
    float2 b = ssq [0][dom][ln];
    #pragma unroll
    for (int gg = 1; gg < 4; ++gg) {
      const float2 a1 = ssum[gg][dom][ln];
      const float2 b1 = ssq [gg][dom][ln];
      a.x += a1.x; a.y += a1.y;
      b.x += b1.x; b.y += b1.y;
    }
    ssum[0][dom][ln] = a;
    ssq [0][dom][ln] = b;
  }
  __syncthreads();

  {
    float2* ps = (float2*)part_sum;
    float2* pq = (float2*)part_sq;
    const size_t base = (size_t)by * ND_ * (C_ / 2);
    for (int idx = tid; idx < ND_ * 64; idx += 256) {
      const int dom = idx >> 6;
      const int ln  = idx & 63;
      const size_t o = base + dom * (C_ / 2) + bx * 64 + ln;
      ps[o] = ssum[0][dom][ln];
      pq[o] = ssq [0][dom][ln];
    }
    if (bx == 0 && tid < ND_) pcnt[by * ND_ + tid] = scnt[tid];
  }

  __threadfence();
  cg::this_grid().sync();

  // ---------------- phase 2: partials -> scale/shift (blocks 0..255) ------
  if (bid < (ND_ * C_) / 32) {
    const int lane2 = tid & 31;
    const int seg   = tid >> 5;        // 0..7
    const int out0  = bid * 32;
    const int gid   = out0 + lane2;
    const int dom   = out0 >> 9;
    const int c     = gid & (C_ - 1);
    const int cpl   = (nchunk + 7) / 8;

    float s = 0.f, q = 0.f;
    int   cn = 0;
    for (int k = 0; k < cpl; ++k) {
      const int ch = seg * cpl + k;
      if (ch < nchunk) {
        const size_t o = ((size_t)ch * ND_ + dom) * C_ + c;
        s += part_sum[o];
        q += part_sq[o];
        cn += pcnt[ch * ND_ + dom];
      }
    }
    fsum[seg][lane2] = s;
    fsq [seg][lane2] = q;
    if (lane2 == 0) fcnt[seg] = cn;
    __syncthreads();

    if (tid < 32) {
      float S = 0.f, Q = 0.f;
      int CN = 0;
      #pragma unroll
      for (int sg = 0; sg < 8; ++sg) {
        S += fsum[sg][tid];
        Q += fsq [sg][tid];
        CN += fcnt[sg];
      }
      const float fc   = fmaxf((float)CN, 1.f);
      const float mean = S / fc;
      const float var  = Q / fc - mean * mean;
      const float inv  = rsqrtf(var + EPS_);
      const int   gg   = out0 + tid;
      const float sc   = inv * gamma[gg];
      scale[gg] = sc;
      shift[gg] = fmaf(-mean, sc, beta[gg]);
    }
  }
}

// ---------------- Kernel 2: normalize ------------------------------------
// Grid-stride float4, plain loads/stores (nt hurt -8us in R6; L3 already
// serves the X re-read per R7's FETCH evidence).
__global__ __launch_bounds__(256) void k_norm(
    const float4* __restrict__ X4, const int* __restrict__ dd,
    const float4* __restrict__ scale4, const float4* __restrict__ shift4,
    float4* __restrict__ Y4, int total4) {
  int i = blockIdx.x * 256 + threadIdx.x;
  const int stride = gridDim.x * 256;
  for (; i < total4; i += stride) {
    const int n  = i >> 7;          // C/4 = 128 float4 per row
    const int c4 = i & 127;
    const int dn = dd[n];           // wave-uniform (128 float4 per row)
    const float4 x  = X4[i];
    const float4 sc = scale4[dn * (C_ / 4) + c4];
    const float4 sh = shift4[dn * (C_ / 4) + c4];
    float4 y;
    y.x = fmaf(x.x, sc.x, sh.x);
    y.y = fmaf(x.y, sc.y, sh.y);
    y.z = fmaf(x.z, sc.z, sh.z);
    y.w = fmaf(x.w, sc.w, sh.w);
    Y4[i] = y;
  }
}

extern "C" void kernel_launch(void* const* d_in, const int* in_sizes, int n_in,
                              void* d_out, int out_size, void* d_ws, size_t ws_size,
                              hipStream_t stream) {
  const float2* X2    = (const float2*)d_in[0];
  const int*    dd    = (const int*)  d_in[1];
  // d_in[2] = parameter_t, d_in[3] = fm_mean : unused by the reference math
  const float*  gamma = (const float*)d_in[4];
  const float*  beta  = (const float*)d_in[5];
  float*        out   = (float*)d_out;

  int N = in_sizes[1];                        // 65536
  const int NCHUNK = (N + RPC - 1) / RPC;     // 128

  // Partials live in d_out (scratch until k_norm overwrites it):
  float* part_sum = out;
  float* part_sq  = out + (size_t)NCHUNK * ND_ * C_;
  int*   pcnt     = (int*)(part_sq + (size_t)NCHUNK * ND_ * C_);
  // scale/shift must survive into k_norm -> d_ws (64 KB).
  float* scale = (float*)d_ws;
  float* shift = scale + ND_ * C_;

  void* args[] = {(void*)&X2, (void*)&dd, (void*)&gamma, (void*)&beta,
                  (void*)&part_sum, (void*)&part_sq, (void*)&pcnt,
                  (void*)&scale, (void*)&shift, (void*)&N};
  hipLaunchCooperativeKernel((const void*)k_stats_fin, dim3(4 * NCHUNK),
                             dim3(256), args, 0, stream);

  const int total4 = N * (C_ / 4);
  int blocks = (total4 + 255) / 256;
  if (blocks > 2048) blocks = 2048;
  k_norm<<<blocks, 256, 0, stream>>>((const float4*)X2, dd,
                                     (const float4*)scale,
                                     (const float4*)shift,
                                     (float4*)out, total4);
}

// Round 10
// 77.478 us; speedup vs baseline: 2.2015x; 2.2015x over previous
//
#include <hip/hip_runtime.h>

constexpr int   ND_  = 16;
constexpr int   C_   = 512;
constexpr float EPS_ = 1e-5f;
constexpr int   RPC  = 1024;  // rows per chunk (NCHUNK=64, partials 8.4 MB RW)

// ---------------- Kernel 1: per-chunk partial stats -----------------------
// grid = (4, N/RPC) = (4,64) = 256 blocks; block = 256 thr = 4 row-groups
// x 64 float2-lanes. Block (bx, by): channel quarter bx of rows
// [by*1024, +1024); each row-group covers 256 rows into its own LDS set,
// merged, dumped once -> NCHUNK=64 partials. 66 KB LDS -> 2 blocks/CU ->
// 8 waves/CU. (Refuted: R4 global atomics, R6 nt, R7/R9 cooperative launch
// — coop runs this same code 5x slower, 25 -> 131 us.)
__global__ __launch_bounds__(256) void k_stats(
    const float2* __restrict__ X2, const int* __restrict__ dd,
    float* __restrict__ part_sum, float* __restrict__ part_sq,
    int* __restrict__ pcnt, int N) {
  __shared__ float2 ssum[4][ND_][64];   // 32 KB
  __shared__ float2 ssq [4][ND_][64];   // 32 KB
  __shared__ int    sd[RPC];            // 4 KB
  __shared__ int    scnt[ND_];

  const int tid  = threadIdx.x;
  const int g    = tid >> 6;        // row-group 0..3
  const int lane = tid & 63;        // float2 lane within quarter
  const int bx   = blockIdx.x;      // channel quarter 0..3
  const int by   = blockIdx.y;      // row chunk

  for (int i = tid; i < 4 * ND_ * 64; i += 256) {
    ((float2*)ssum)[i] = make_float2(0.f, 0.f);
    ((float2*)ssq )[i] = make_float2(0.f, 0.f);
  }
  if (tid < ND_) scnt[tid] = 0;
  __syncthreads();

  const int r0 = by * RPC;
  const int r1 = min(N, r0 + RPC);
  const int nr = r1 - r0;

  for (int i = tid; i < nr; i += 256) {
    const int v = dd[r0 + i];
    sd[i] = v;
    if (bx == 0) atomicAdd(&scnt[v], 1);
  }
  __syncthreads();

  const int rows_per_group = RPC / 4;     // 256
  const int jr0 = g * rows_per_group;
  const int jr1 = min(nr, jr0 + rows_per_group);
  const int ch2 = bx * 64 + lane;   // float2 column (row = 256 float2)
  #pragma unroll 8
  for (int j = jr0; j < jr1; ++j) {
    const int    dn = sd[j];        // wave-uniform
    const float2 v  = X2[(size_t)(r0 + j) * (C_ / 2) + ch2];
    float2 a = ssum[g][dn][lane];
    a.x += v.x; a.y += v.y;
    ssum[g][dn][lane] = a;
    float2 b = ssq[g][dn][lane];
    b.x = fmaf(v.x, v.x, b.x);
    b.y = fmaf(v.y, v.y, b.y);
    ssq[g][dn][lane] = b;
  }
  __syncthreads();

  // merge groups 1..3 into 0, parallel over all 256 threads (ND*64 = 1024)
  for (int idx = tid; idx < ND_ * 64; idx += 256) {
    const int dom = idx >> 6;
    const int ln  = idx & 63;
    float2 a = ssum[0][dom][ln];
    float2 b = ssq [0][dom][ln];
    #pragma unroll
    for (int gg = 1; gg < 4; ++gg) {
      const float2 a1 = ssum[gg][dom][ln];
      const float2 b1 = ssq [gg][dom][ln];
      a.x += a1.x; a.y += a1.y;
      b.x += b1.x; b.y += b1.y;
    }
    ssum[0][dom][ln] = a;
    ssq [0][dom][ln] = b;
  }
  __syncthreads();

  float2* ps = (float2*)part_sum;
  float2* pq = (float2*)part_sq;
  const size_t base = (size_t)by * ND_ * (C_ / 2);
  for (int idx = tid; idx < ND_ * 64; idx += 256) {
    const int dom = idx >> 6;
    const int ln  = idx & 63;
    const size_t o = base + dom * (C_ / 2) + bx * 64 + ln;
    ps[o] = ssum[0][dom][ln];
    pq[o] = ssq [0][dom][ln];
  }
  if (bx == 0 && tid < ND_) pcnt[by * ND_ + tid] = scnt[tid];
}

// ---------------- Kernel 2: reduce partials -> scale/shift ----------------
// grid = (ND_*C_)/32 = 256 blocks x 256 threads; block owns 32 outputs,
// 8 chunk-segments per output reduced via LDS. nchunk = 64.
__global__ __launch_bounds__(256) void k_finalize(
    const float* __restrict__ part_sum, const float* __restrict__ part_sq,
    const int* __restrict__ pcnt, const float* __restrict__ gamma,
    const float* __restrict__ beta, float* __restrict__ scale,
    float* __restrict__ shift, int nchunk) {
  __shared__ float ssum[8][32];
  __shared__ float ssq [8][32];
  __shared__ int   scnt[8];

  const int t     = threadIdx.x;
  const int lane  = t & 31;
  const int seg   = t >> 5;
  const int out0  = blockIdx.x * 32;
  const int gid   = out0 + lane;
  const int dom   = out0 >> 9;
  const int c     = gid & (C_ - 1);
  const int cpl   = (nchunk + 7) / 8;

  float s = 0.f, q = 0.f;
  int   cn = 0;
  for (int k = 0; k < cpl; ++k) {
    const int ch = seg * cpl + k;
    if (ch < nchunk) {
      const size_t o = ((size_t)ch * ND_ + dom) * C_ + c;
      s += part_sum[o];
      q += part_sq[o];
      cn += pcnt[ch * ND_ + dom];
    }
  }
  ssum[seg][lane] = s;
  ssq [seg][lane] = q;
  if (lane == 0) scnt[seg] = cn;
  __syncthreads();

  if (t < 32) {
    float S = 0.f, Q = 0.f;
    #pragma unroll
    for (int sg = 0; sg < 8; ++sg) { S += ssum[sg][t]; Q += ssq[sg][t]; }
    int CN = 0;
    #pragma unroll
    for (int sg = 0; sg < 8; ++sg) CN += scnt[sg];
    const float fc   = fmaxf((float)CN, 1.f);
    const float mean = S / fc;
    const float var  = Q / fc - mean * mean;
    const float inv  = rsqrtf(var + EPS_);
    const int   g    = out0 + t;
    const float sc   = inv * gamma[g];
    scale[g] = sc;
    shift[g] = fmaf(-mean, sc, beta[g]);
  }
}

// ---------------- Kernel 3: normalize ------------------------------------
// Grid-stride float4, plain loads/stores (nt hurt -8us in R6; memory-side
// L3 already serves the X re-read, confirmed by R7's FETCH_SIZE).
__global__ __launch_bounds__(256) void k_norm(
    const float4* __restrict__ X4, const int* __restrict__ dd,
    const float4* __restrict__ scale4, const float4* __restrict__ shift4,
    float4* __restrict__ Y4, int total4) {
  int i = blockIdx.x * 256 + threadIdx.x;
  const int stride = gridDim.x * 256;
  for (; i < total4; i += stride) {
    const int n  = i >> 7;          // C/4 = 128 float4 per row
    const int c4 = i & 127;
    const int dn = dd[n];           // wave-uniform (128 float4 per row)
    const float4 x  = X4[i];
    const float4 sc = scale4[dn * (C_ / 4) + c4];
    const float4 sh = shift4[dn * (C_ / 4) + c4];
    float4 y;
    y.x = fmaf(x.x, sc.x, sh.x);
    y.y = fmaf(x.y, sc.y, sh.y);
    y.z = fmaf(x.z, sc.z, sh.z);
    y.w = fmaf(x.w, sc.w, sh.w);
    Y4[i] = y;
  }
}

extern "C" void kernel_launch(void* const* d_in, const int* in_sizes, int n_in,
                              void* d_out, int out_size, void* d_ws, size_t ws_size,
                              hipStream_t stream) {
  const float* X     = (const float*)d_in[0];
  const int*   dd    = (const int*)  d_in[1];
  // d_in[2] = parameter_t, d_in[3] = fm_mean : unused by the reference math
  const float* gamma = (const float*)d_in[4];
  const float* beta  = (const float*)d_in[5];
  float*       out   = (float*)d_out;

  const int N      = in_sizes[1];             // 65536
  const int NCHUNK = (N + RPC - 1) / RPC;     // 64

  // Partials live in d_out (scratch until k_norm overwrites it):
  //   part_sum[NCHUNK][16][512], part_sq[NCHUNK][16][512], pcnt[NCHUNK][16]
  float* part_sum = out;
  float* part_sq  = out + (size_t)NCHUNK * ND_ * C_;
  int*   pcnt     = (int*)(part_sq + (size_t)NCHUNK * ND_ * C_);
  // scale/shift must survive k_norm -> keep in d_ws (64 KB).
  float* scale = (float*)d_ws;
  float* shift = scale + ND_ * C_;

  dim3 g1(4, NCHUNK);
  k_stats<<<g1, 256, 0, stream>>>((const float2*)X, dd, part_sum, part_sq,
                                  pcnt, N);
  k_finalize<<<(ND_ * C_) / 32, 256, 0, stream>>>(
      part_sum, part_sq, pcnt, gamma, beta, scale, shift, NCHUNK);

  const int total4 = N * (C_ / 4);
  int blocks = (total4 + 255) / 256;
  if (blocks > 2048) blocks = 2048;
  k_norm<<<blocks, 256, 0, stream>>>((const float4*)X, dd,
                                     (const float4*)scale,
                                     (const float4*)shift,
                                     (float4*)out, total4);
}

// Round 11
// 73.992 us; speedup vs baseline: 2.3052x; 1.0471x over previous
//
#include <hip/hip_runtime.h>

constexpr int   ND_  = 16;
constexpr int   C_   = 512;
constexpr float EPS_ = 1e-5f;
constexpr int   RPC  = 1024;  // rows per chunk (NCHUNK=64, partials 8.4 MB RW)

// ---------------- Kernel 1: per-chunk partial stats -----------------------
// grid = (4, N/RPC) = (4,64) = 256 blocks; block = 512 thr = 8 row-groups
// x 64 float2-lanes (R10 used 256 thr -> 1 block/CU = 4 waves/CU, latency-
// limited ~5.2 TB/s; 512 thr restores 8 waves/CU at 132 KB LDS, 1 block/CU).
// Block (bx, by): channel quarter bx of rows [by*1024, +1024); each row-group
// covers 128 rows into its own LDS set, merged, dumped -> NCHUNK=64 partials.
// (Refuted: R4 global atomics, R6 nt-both, R7/R9 cooperative launch.)
__global__ __launch_bounds__(512) void k_stats(
    const float2* __restrict__ X2, const int* __restrict__ dd,
    float* __restrict__ part_sum, float* __restrict__ part_sq,
    int* __restrict__ pcnt, int N) {
  __shared__ float2 ssum[8][ND_][64];   // 64 KB
  __shared__ float2 ssq [8][ND_][64];   // 64 KB
  __shared__ int    sd[RPC];            // 4 KB
  __shared__ int    scnt[ND_];

  const int tid  = threadIdx.x;
  const int g    = tid >> 6;        // row-group 0..7
  const int lane = tid & 63;        // float2 lane within quarter
  const int bx   = blockIdx.x;      // channel quarter 0..3
  const int by   = blockIdx.y;      // row chunk

  for (int i = tid; i < 8 * ND_ * 64; i += 512) {
    ((float2*)ssum)[i] = make_float2(0.f, 0.f);
    ((float2*)ssq )[i] = make_float2(0.f, 0.f);
  }
  if (tid < ND_) scnt[tid] = 0;
  __syncthreads();

  const int r0 = by * RPC;
  const int r1 = min(N, r0 + RPC);
  const int nr = r1 - r0;

  for (int i = tid; i < nr; i += 512) {
    const int v = dd[r0 + i];
    sd[i] = v;
    if (bx == 0) atomicAdd(&scnt[v], 1);
  }
  __syncthreads();

  const int rows_per_group = RPC / 8;     // 128
  const int jr0 = g * rows_per_group;
  const int jr1 = min(nr, jr0 + rows_per_group);
  const int ch2 = bx * 64 + lane;   // float2 column (row = 256 float2)
  #pragma unroll 8
  for (int j = jr0; j < jr1; ++j) {
    const int    dn = sd[j];        // wave-uniform
    const float2 v  = X2[(size_t)(r0 + j) * (C_ / 2) + ch2];
    float2 a = ssum[g][dn][lane];
    a.x += v.x; a.y += v.y;
    ssum[g][dn][lane] = a;
    float2 b = ssq[g][dn][lane];
    b.x = fmaf(v.x, v.x, b.x);
    b.y = fmaf(v.y, v.y, b.y);
    ssq[g][dn][lane] = b;
  }
  __syncthreads();

  // merge groups 1..7 into 0, parallel over all 512 threads (ND*64 = 1024)
  for (int idx = tid; idx < ND_ * 64; idx += 512) {
    const int dom = idx >> 6;
    const int ln  = idx & 63;
    float2 a = ssum[0][dom][ln];
    float2 b = ssq [0][dom][ln];
    #pragma unroll
    for (int gg = 1; gg < 8; ++gg) {
      const float2 a1 = ssum[gg][dom][ln];
      const float2 b1 = ssq [gg][dom][ln];
      a.x += a1.x; a.y += a1.y;
      b.x += b1.x; b.y += b1.y;
    }
    ssum[0][dom][ln] = a;
    ssq [0][dom][ln] = b;
  }
  __syncthreads();

  float2* ps = (float2*)part_sum;
  float2* pq = (float2*)part_sq;
  const size_t base = (size_t)by * ND_ * (C_ / 2);
  for (int idx = tid; idx < ND_ * 64; idx += 512) {
    const int dom = idx >> 6;
    const int ln  = idx & 63;
    const size_t o = base + dom * (C_ / 2) + bx * 64 + ln;
    ps[o] = ssum[0][dom][ln];
    pq[o] = ssq [0][dom][ln];
  }
  if (bx == 0 && tid < ND_) pcnt[by * ND_ + tid] = scnt[tid];
}

// ---------------- Kernel 2: reduce partials -> scale/shift ----------------
// grid = (ND_*C_)/32 = 256 blocks x 256 threads; block owns 32 outputs,
// 8 chunk-segments per output reduced via LDS. nchunk = 64.
__global__ __launch_bounds__(256) void k_finalize(
    const float* __restrict__ part_sum, const float* __restrict__ part_sq,
    const int* __restrict__ pcnt, const float* __restrict__ gamma,
    const float* __restrict__ beta, float* __restrict__ scale,
    float* __restrict__ shift, int nchunk) {
  __shared__ float ssum[8][32];
  __shared__ float ssq [8][32];
  __shared__ int   scnt[8];

  const int t     = threadIdx.x;
  const int lane  = t & 31;
  const int seg   = t >> 5;
  const int out0  = blockIdx.x * 32;
  const int gid   = out0 + lane;
  const int dom   = out0 >> 9;
  const int c     = gid & (C_ - 1);
  const int cpl   = (nchunk + 7) / 8;

  float s = 0.f, q = 0.f;
  int   cn = 0;
  for (int k = 0; k < cpl; ++k) {
    const int ch = seg * cpl + k;
    if (ch < nchunk) {
      const size_t o = ((size_t)ch * ND_ + dom) * C_ + c;
      s += part_sum[o];
      q += part_sq[o];
      cn += pcnt[ch * ND_ + dom];
    }
  }
  ssum[seg][lane] = s;
  ssq [seg][lane] = q;
  if (lane == 0) scnt[seg] = cn;
  __syncthreads();

  if (t < 32) {
    float S = 0.f, Q = 0.f;
    #pragma unroll
    for (int sg = 0; sg < 8; ++sg) { S += ssum[sg][t]; Q += ssq[sg][t]; }
    int CN = 0;
    #pragma unroll
    for (int sg = 0; sg < 8; ++sg) CN += scnt[sg];
    const float fc   = fmaxf((float)CN, 1.f);
    const float mean = S / fc;
    const float var  = Q / fc - mean * mean;
    const float inv  = rsqrtf(var + EPS_);
    const int   g    = out0 + t;
    const float sc   = inv * gamma[g];
    scale[g] = sc;
    shift[g] = fmaf(-mean, sc, beta[g]);
  }
}

// ---------------- Kernel 3: normalize ------------------------------------
// Grid-stride float4, plain loads/stores (nt-both hurt -8us in R6).
__global__ __launch_bounds__(256) void k_norm(
    const float4* __restrict__ X4, const int* __restrict__ dd,
    const float4* __restrict__ scale4, const float4* __restrict__ shift4,
    float4* __restrict__ Y4, int total4) {
  int i = blockIdx.x * 256 + threadIdx.x;
  const int stride = gridDim.x * 256;
  for (; i < total4; i += stride) {
    const int n  = i >> 7;          // C/4 = 128 float4 per row
    const int c4 = i & 127;
    const int dn = dd[n];           // wave-uniform (128 float4 per row)
    const float4 x  = X4[i];
    const float4 sc = scale4[dn * (C_ / 4) + c4];
    const float4 sh = shift4[dn * (C_ / 4) + c4];
    float4 y;
    y.x = fmaf(x.x, sc.x, sh.x);
    y.y = fmaf(x.y, sc.y, sh.y);
    y.z = fmaf(x.z, sc.z, sh.z);
    y.w = fmaf(x.w, sc.w, sh.w);
    Y4[i] = y;
  }
}

extern "C" void kernel_launch(void* const* d_in, const int* in_sizes, int n_in,
                              void* d_out, int out_size, void* d_ws, size_t ws_size,
                              hipStream_t stream) {
  const float* X     = (const float*)d_in[0];
  const int*   dd    = (const int*)  d_in[1];
  // d_in[2] = parameter_t, d_in[3] = fm_mean : unused by the reference math
  const float* gamma = (const float*)d_in[4];
  const float* beta  = (const float*)d_in[5];
  float*       out   = (float*)d_out;

  const int N      = in_sizes[1];             // 65536
  const int NCHUNK = (N + RPC - 1) / RPC;     // 64

  // Partials live in d_out (scratch until k_norm overwrites it):
  //   part_sum[NCHUNK][16][512], part_sq[NCHUNK][16][512], pcnt[NCHUNK][16]
  float* part_sum = out;
  float* part_sq  = out + (size_t)NCHUNK * ND_ * C_;
  int*   pcnt     = (int*)(part_sq + (size_t)NCHUNK * ND_ * C_);
  // scale/shift must survive k_norm -> keep in d_ws (64 KB).
  float* scale = (float*)d_ws;
  float* shift = scale + ND_ * C_;

  dim3 g1(4, NCHUNK);
  k_stats<<<g1, 512, 0, stream>>>((const float2*)X, dd, part_sum, part_sq,
                                  pcnt, N);
  k_finalize<<<(ND_ * C_) / 32, 256, 0, stream>>>(
      part_sum, part_sq, pcnt, gamma, beta, scale, shift, NCHUNK);

  const int total4 = N * (C_ / 4);
  int blocks = (total4 + 255) / 256;
  if (blocks > 2048) blocks = 2048;
  k_norm<<<blocks, 256, 0, stream>>>((const float4*)X, dd,
                                     (const float4*)scale,
                                     (const float4*)shift,
                                     (float4*)out, total4);
}

// Round 12
// 73.632 us; speedup vs baseline: 2.3165x; 1.0049x over previous
//
#include <hip/hip_runtime.h>

constexpr int   ND_  = 16;
constexpr int   C_   = 512;
constexpr float EPS_ = 1e-5f;
constexpr int   RPC  = 1024;  // rows per chunk (NCHUNK=64, partials 8.4 MB RW)

typedef float v4f __attribute__((ext_vector_type(4)));  // clang-native for nontemporal builtin

// ---------------- Kernel 1: per-chunk partial stats -----------------------
// grid = (4, N/RPC) = (4,64) = 256 blocks; block = 512 thr = 8 row-groups
// x 64 float2-lanes; 132 KB LDS -> 1 block/CU, 8 waves/CU (R11: this was
// worth 3.5us over 256 thr). Block (bx, by): channel quarter bx of rows
// [by*1024, +1024); per-group LDS accumulators, merged, dumped.
// (Refuted: R4 global atomics, R6 nt-both, R7/R9 cooperative launch.)
__global__ __launch_bounds__(512) void k_stats(
    const float2* __restrict__ X2, const int* __restrict__ dd,
    float* __restrict__ part_sum, float* __restrict__ part_sq,
    int* __restrict__ pcnt, int N) {
  __shared__ float2 ssum[8][ND_][64];   // 64 KB
  __shared__ float2 ssq [8][ND_][64];   // 64 KB
  __shared__ int    sd[RPC];            // 4 KB
  __shared__ int    scnt[ND_];

  const int tid  = threadIdx.x;
  const int g    = tid >> 6;        // row-group 0..7
  const int lane = tid & 63;        // float2 lane within quarter
  const int bx   = blockIdx.x;      // channel quarter 0..3
  const int by   = blockIdx.y;      // row chunk

  for (int i = tid; i < 8 * ND_ * 64; i += 512) {
    ((float2*)ssum)[i] = make_float2(0.f, 0.f);
    ((float2*)ssq )[i] = make_float2(0.f, 0.f);
  }
  if (tid < ND_) scnt[tid] = 0;
  __syncthreads();

  const int r0 = by * RPC;
  const int r1 = min(N, r0 + RPC);
  const int nr = r1 - r0;

  for (int i = tid; i < nr; i += 512) {
    const int v = dd[r0 + i];
    sd[i] = v;
    if (bx == 0) atomicAdd(&scnt[v], 1);
  }
  __syncthreads();

  const int rows_per_group = RPC / 8;     // 128
  const int jr0 = g * rows_per_group;
  const int jr1 = min(nr, jr0 + rows_per_group);
  const int ch2 = bx * 64 + lane;   // float2 column (row = 256 float2)
  #pragma unroll 8
  for (int j = jr0; j < jr1; ++j) {
    const int    dn = sd[j];        // wave-uniform
    const float2 v  = X2[(size_t)(r0 + j) * (C_ / 2) + ch2];
    float2 a = ssum[g][dn][lane];
    a.x += v.x; a.y += v.y;
    ssum[g][dn][lane] = a;
    float2 b = ssq[g][dn][lane];
    b.x = fmaf(v.x, v.x, b.x);
    b.y = fmaf(v.y, v.y, b.y);
    ssq[g][dn][lane] = b;
  }
  __syncthreads();

  // merge groups 1..7 into 0, parallel over all 512 threads (ND*64 = 1024)
  for (int idx = tid; idx < ND_ * 64; idx += 512) {
    const int dom = idx >> 6;
    const int ln  = idx & 63;
    float2 a = ssum[0][dom][ln];
    float2 b = ssq [0][dom][ln];
    #pragma unroll
    for (int gg = 1; gg < 8; ++gg) {
      const float2 a1 = ssum[gg][dom][ln];
      const float2 b1 = ssq [gg][dom][ln];
      a.x += a1.x; a.y += a1.y;
      b.x += b1.x; b.y += b1.y;
    }
    ssum[0][dom][ln] = a;
    ssq [0][dom][ln] = b;
  }
  __syncthreads();

  float2* ps = (float2*)part_sum;
  float2* pq = (float2*)part_sq;
  const size_t base = (size_t)by * ND_ * (C_ / 2);
  for (int idx = tid; idx < ND_ * 64; idx += 512) {
    const int dom = idx >> 6;
    const int ln  = idx & 63;
    const size_t o = base + dom * (C_ / 2) + bx * 64 + ln;
    ps[o] = ssum[0][dom][ln];
    pq[o] = ssq [0][dom][ln];
  }
  if (bx == 0 && tid < ND_) pcnt[by * ND_ + tid] = scnt[tid];
}

// ---------------- Kernel 2: reduce partials -> scale/shift ----------------
// grid = (ND_*C_)/32 = 256 blocks x 256 threads; block owns 32 outputs,
// 8 chunk-segments per output reduced via LDS. nchunk = 64.
__global__ __launch_bounds__(256) void k_finalize(
    const float* __restrict__ part_sum, const float* __restrict__ part_sq,
    const int* __restrict__ pcnt, const float* __restrict__ gamma,
    const float* __restrict__ beta, float* __restrict__ scale,
    float* __restrict__ shift, int nchunk) {
  __shared__ float ssum[8][32];
  __shared__ float ssq [8][32];
  __shared__ int   scnt[8];

  const int t     = threadIdx.x;
  const int lane  = t & 31;
  const int seg   = t >> 5;
  const int out0  = blockIdx.x * 32;
  const int gid   = out0 + lane;
  const int dom   = out0 >> 9;
  const int c     = gid & (C_ - 1);
  const int cpl   = (nchunk + 7) / 8;

  float s = 0.f, q = 0.f;
  int   cn = 0;
  for (int k = 0; k < cpl; ++k) {
    const int ch = seg * cpl + k;
    if (ch < nchunk) {
      const size_t o = ((size_t)ch * ND_ + dom) * C_ + c;
      s += part_sum[o];
      q += part_sq[o];
      cn += pcnt[ch * ND_ + dom];
    }
  }
  ssum[seg][lane] = s;
  ssq [seg][lane] = q;
  if (lane == 0) scnt[seg] = cn;
  __syncthreads();

  if (t < 32) {
    float S = 0.f, Q = 0.f;
    #pragma unroll
    for (int sg = 0; sg < 8; ++sg) { S += ssum[sg][t]; Q += ssq[sg][t]; }
    int CN = 0;
    #pragma unroll
    for (int sg = 0; sg < 8; ++sg) CN += scnt[sg];
    const float fc   = fmaxf((float)CN, 1.f);
    const float mean = S / fc;
    const float var  = Q / fc - mean * mean;
    const float inv  = rsqrtf(var + EPS_);
    const int   g    = out0 + t;
    const float sc   = inv * gamma[g];
    scale[g] = sc;
    shift[g] = fmaf(-mean, sc, beta[g]);
  }
}

// ---------------- Kernel 3: normalize ------------------------------------
// Grid-stride float4. Plain (cached) X loads — X should be L3-resident from
// k_stats; R6's regression likely came from nt LOADS bypassing those hits.
// NT stores for Y only: write-once data, keep its write-allocations from
// evicting X mid-pass.
__global__ __launch_bounds__(256) void k_norm(
    const float4* __restrict__ X4, const int* __restrict__ dd,
    const float4* __restrict__ scale4, const float4* __restrict__ shift4,
    v4f* __restrict__ Y4, int total4) {
  int i = blockIdx.x * 256 + threadIdx.x;
  const int stride = gridDim.x * 256;
  for (; i < total4; i += stride) {
    const int n  = i >> 7;          // C/4 = 128 float4 per row
    const int c4 = i & 127;
    const int dn = dd[n];           // wave-uniform (128 float4 per row)
    const float4 x  = X4[i];
    const float4 sc = scale4[dn * (C_ / 4) + c4];
    const float4 sh = shift4[dn * (C_ / 4) + c4];
    v4f y;
    y.x = fmaf(x.x, sc.x, sh.x);
    y.y = fmaf(x.y, sc.y, sh.y);
    y.z = fmaf(x.z, sc.z, sh.z);
    y.w = fmaf(x.w, sc.w, sh.w);
    __builtin_nontemporal_store(y, &Y4[i]);
  }
}

extern "C" void kernel_launch(void* const* d_in, const int* in_sizes, int n_in,
                              void* d_out, int out_size, void* d_ws, size_t ws_size,
                              hipStream_t stream) {
  const float* X     = (const float*)d_in[0];
  const int*   dd    = (const int*)  d_in[1];
  // d_in[2] = parameter_t, d_in[3] = fm_mean : unused by the reference math
  const float* gamma = (const float*)d_in[4];
  const float* beta  = (const float*)d_in[5];
  float*       out   = (float*)d_out;

  const int N      = in_sizes[1];             // 65536
  const int NCHUNK = (N + RPC - 1) / RPC;     // 64

  // Partials live in d_out (scratch until k_norm overwrites it):
  //   part_sum[NCHUNK][16][512], part_sq[NCHUNK][16][512], pcnt[NCHUNK][16]
  float* part_sum = out;
  float* part_sq  = out + (size_t)NCHUNK * ND_ * C_;
  int*   pcnt     = (int*)(part_sq + (size_t)NCHUNK * ND_ * C_);
  // scale/shift must survive k_norm -> keep in d_ws (64 KB).
  float* scale = (float*)d_ws;
  float* shift = scale + ND_ * C_;

  dim3 g1(4, NCHUNK);
  k_stats<<<g1, 512, 0, stream>>>((const float2*)X, dd, part_sum, part_sq,
                                  pcnt, N);
  k_finalize<<<(ND_ * C_) / 32, 256, 0, stream>>>(
      part_sum, part_sq, pcnt, gamma, beta, scale, shift, NCHUNK);

  const int total4 = N * (C_ / 4);
  int blocks = (total4 + 255) / 256;
  if (blocks > 2048) blocks = 2048;
  k_norm<<<blocks, 256, 0, stream>>>((const float4*)X, dd,
                                     (const float4*)scale,
                                     (const float4*)shift,
                                     (v4f*)out, total4);
}